// Round 1
// 150.167 us; speedup vs baseline: 1.0135x; 1.0135x over previous
//
#include <hip/hip_runtime.h>

// SPD loss: 18-bin (9 class x 2 group) histogram over 16.7M int32 pairs + tiny epilogue.
// R0: scattered LDS atomics -> 55 us.
// R1: register-packed histogram, same 55 us; warm==cold -> not LDS, not HBM.
// R2: removed global atomics -> 45 us, but warm==cold persists at 1.4 TB/s:
//     latency/MLP-bound — only 2 loads in flight per wave.
// R3: "issue all 16 loads up front" — but VGPR_Count=40 proves the compiler
//     re-serialized: 16 int4 loads need 64 dest VGPRs; at 40 VGPRs it chunked
//     the burst into ~2-load/wait rounds. Still 48 us, warm==cold.
// R4 (this): force the register budget with __launch_bounds__(512,4)
//     (VGPR cap 128, >=4 waves/SIMD). Loads interleaved p/a pairwise so
//     consumption starts at vmcnt(14) rather than a full drain. Also switch
//     to total+group1 accumulation (c0 derived at flush) to trim VALU.
//     Predict: VGPR ~100+, hist 48 -> ~25 us, VALUBusy ~30%.

#define N_CLASSES 9
#define N_GROUPS 2
#define NBINS (N_CLASSES * N_GROUPS)  // 18
#define ITEMS 8                       // int4-pairs per thread per superiteration (32 elems < 127 field cap)

__global__ __launch_bounds__(512, 4) void spd_hist_kernel(
    const int* __restrict__ preds,
    const int* __restrict__ attrs,
    unsigned int* __restrict__ partials,  // [gridDim.x][NBINS]
    int n4, int n)
{
    __shared__ unsigned int lh0[N_CLASSES];
    __shared__ unsigned int lh1[N_CLASSES];
    if (threadIdx.x < N_CLASSES) { lh0[threadIdx.x] = 0u; lh1[threadIdx.x] = 0u; }
    __syncthreads();

    // per-thread 16-bit packed totals: lo16 = group0, hi16 = group1
    unsigned int cnt[N_CLASSES];
    #pragma unroll
    for (int p = 0; p < N_CLASSES; ++p) cnt[p] = 0u;

    const int4* __restrict__ p4 = (const int4*)preds;
    const int4* __restrict__ a4 = (const int4*)attrs;

    const int span = (int)blockDim.x * ITEMS;           // int4s covered by one block-superiteration
    for (int S = blockIdx.x * span; S < n4; S += gridDim.x * span) {
        const int s = S + (int)threadIdx.x;
        // accT: per-class TOTAL count (7-bit fields); acc1: per-class group-1 count.
        unsigned long long accT = 0ull, acc1 = 0ull;

        if (S + span <= n4) {
            // fast path: issue all 16 loads (pairwise p/a) before consuming anything.
            // With the 128-VGPR budget these all stay in flight; consumption of
            // element k only needs vmcnt(14-2k).
            int4 p[ITEMS], a[ITEMS];
            #pragma unroll
            for (int k = 0; k < ITEMS; ++k) {
                p[k] = p4[s + k * (int)blockDim.x];
                a[k] = a4[s + k * (int)blockDim.x];
            }
            #pragma unroll
            for (int k = 0; k < ITEMS; ++k) {
                {
                    unsigned long long inc = 1ull << (7 * p[k].x);
                    accT += inc;
                    acc1 += (a[k].x == 0) ? 0ull : inc;
                }
                {
                    unsigned long long inc = 1ull << (7 * p[k].y);
                    accT += inc;
                    acc1 += (a[k].y == 0) ? 0ull : inc;
                }
                {
                    unsigned long long inc = 1ull << (7 * p[k].z);
                    accT += inc;
                    acc1 += (a[k].z == 0) ? 0ull : inc;
                }
                {
                    unsigned long long inc = 1ull << (7 * p[k].w);
                    accT += inc;
                    acc1 += (a[k].w == 0) ? 0ull : inc;
                }
            }
        } else {
            // masked tail superiteration
            for (int k = 0; k < ITEMS; ++k) {
                const int idx = s + k * (int)blockDim.x;
                if (idx < n4) {
                    int4 pp = p4[idx];
                    int4 aa = a4[idx];
                    {
                        unsigned long long inc = 1ull << (7 * pp.x);
                        accT += inc;
                        acc1 += (aa.x == 0) ? 0ull : inc;
                    }
                    {
                        unsigned long long inc = 1ull << (7 * pp.y);
                        accT += inc;
                        acc1 += (aa.y == 0) ? 0ull : inc;
                    }
                    {
                        unsigned long long inc = 1ull << (7 * pp.z);
                        accT += inc;
                        acc1 += (aa.z == 0) ? 0ull : inc;
                    }
                    {
                        unsigned long long inc = 1ull << (7 * pp.w);
                        accT += inc;
                        acc1 += (aa.w == 0) ? 0ull : inc;
                    }
                }
            }
        }

        // flush 7-bit windows (<=32 per field) into 16-bit packed totals.
        // group0 = total - group1.
        #pragma unroll
        for (int p = 0; p < N_CLASSES; ++p) {
            unsigned int ct = (unsigned int)(accT >> (7 * p)) & 127u;
            unsigned int c1 = (unsigned int)(acc1 >> (7 * p)) & 127u;
            cnt[p] += (ct - c1) | (c1 << 16);
        }
    }

    // scalar remainder (n % 4), block 0 only: <=3 items
    if (blockIdx.x == 0) {
        for (int t = n4 * 4 + (int)threadIdx.x; t < n; t += (int)blockDim.x)
            cnt[preds[t]] += (attrs[t] == 0) ? 1u : 0x10000u;
    }

    // wave-64 butterfly; 16-bit halves hold <=64*32 = 2048 here — no carry
    #pragma unroll
    for (int m = 1; m < 64; m <<= 1) {
        #pragma unroll
        for (int p = 0; p < N_CLASSES; ++p)
            cnt[p] += __shfl_xor(cnt[p], m, 64);
    }

    // wave leaders -> block LDS (u32 per group)
    if ((threadIdx.x & 63) == 0) {
        #pragma unroll
        for (int p = 0; p < N_CLASSES; ++p) {
            atomicAdd(&lh0[p], cnt[p] & 0xFFFFu);
            atomicAdd(&lh1[p], cnt[p] >> 16);
        }
    }
    __syncthreads();

    // plain stores — no global atomics
    if (threadIdx.x < NBINS) {
        int c = threadIdx.x >> 1;
        unsigned int v = (threadIdx.x & 1) ? lh1[c] : lh0[c];
        partials[blockIdx.x * NBINS + threadIdx.x] = v;
    }
}

__global__ __launch_bounds__(1024) void spd_finalize_kernel(
    const unsigned int* __restrict__ partials,
    float* __restrict__ out, int nblocks, double n_total)
{
    __shared__ double counts[NBINS];
    const int tid = threadIdx.x;

    if (tid < NBINS * 32) {
        const int bin = tid >> 5;
        const int j = tid & 31;
        unsigned int s = 0u;
        #pragma unroll 8
        for (int b = j; b < nblocks; b += 32)
            s += partials[b * NBINS + bin];
        #pragma unroll
        for (int m = 1; m < 32; m <<= 1)
            s += __shfl_xor(s, m, 32);
        if (j == 0) counts[bin] = (double)s;
    }
    __syncthreads();

    if (tid == 0) {
        double n1 = 0.0;
        #pragma unroll
        for (int c = 0; c < N_CLASSES; ++c)
            n1 += counts[c * N_GROUPS + 1];
        double n0 = n_total - n1;
        double acc = 0.0;
        #pragma unroll
        for (int c = 0; c < N_CLASSES; ++c) {
            double d = counts[c * N_GROUPS] / n0 - counts[c * N_GROUPS + 1] / n1;
            acc += d * d;
        }
        out[0] = (float)acc;
    }
}

extern "C" void kernel_launch(void* const* d_in, const int* in_sizes, int n_in,
                              void* d_out, int out_size, void* d_ws, size_t ws_size,
                              hipStream_t stream)
{
    const int* preds = (const int*)d_in[0];
    const int* attrs = (const int*)d_in[1];
    const int n = in_sizes[0];

    unsigned int* partials = (unsigned int*)d_ws;

    const int n4 = n / 4;
    const int block = 512;
    const int per_block = block * ITEMS;              // int4s per block-superiteration
    int grid = (n4 + per_block - 1) / per_block;      // 1024 for N=16.7M
    if (grid > 2048) grid = 2048;
    int max_grid = (int)(ws_size / (NBINS * sizeof(unsigned int)));
    if (grid > max_grid) grid = max_grid;
    if (grid < 1) grid = 1;

    spd_hist_kernel<<<grid, block, 0, stream>>>(preds, attrs, partials, n4, n);
    spd_finalize_kernel<<<1, 1024, 0, stream>>>(partials, (float*)d_out, grid, (double)n);
}

// Round 2
// 147.480 us; speedup vs baseline: 1.0320x; 1.0182x over previous
//
#include <hip/hip_runtime.h>

// SPD loss: 18-bin (9 class x 2 group) histogram over 16.7M int32 pairs + tiny epilogue.
// R0: scattered LDS atomics -> 55 us.
// R1: register-packed histogram, same 55 us; warm==cold -> not LDS, not HBM.
// R2: removed global atomics -> 45 us, warm==cold at 1.4 TB/s: latency/MLP-bound.
// R3: "issue all 16 loads up front" in source — VGPR_Count=40: compiler re-serialized.
// R4: __launch_bounds__(512,4) to raise the VGPR cap — VGPR STILL 40, dur unchanged.
//     Lesson: launch_bounds grants permission; the scheduler still sinks loads to
//     their uses. Permission != force.
// R5 (this): FORCE the burst with an inline-asm register pin: load 16 int4s into
//     named ext_vector regs, then one asm volatile consuming all 16 quads ("+v").
//     All 64 dest VGPRs are simultaneously live at that point -> compiler must
//     issue all 16 loads then a single s_waitcnt vmcnt(0): ONE latency exposure
//     per superiteration instead of ~16. launch_bounds(512,3) for headroom.
//     Predict: VGPR 40 -> ~110-130, hist 47 -> ~22-28 us, warm < cold.
//     If VGPR rises but dur stays 47: per-wave MLP theory is dead -> pivot.

#define N_CLASSES 9
#define N_GROUPS 2
#define NBINS (N_CLASSES * N_GROUPS)  // 18
#define ITEMS 8                       // int4-pairs per thread per superiteration (32 elems < 127 field cap)
#define BDIM 512

typedef int vint4 __attribute__((ext_vector_type(4)));

__global__ __launch_bounds__(BDIM, 3) void spd_hist_kernel(
    const int* __restrict__ preds,
    const int* __restrict__ attrs,
    unsigned int* __restrict__ partials,  // [gridDim.x][NBINS]
    int n4, int n)
{
    __shared__ unsigned int lh0[N_CLASSES];
    __shared__ unsigned int lh1[N_CLASSES];
    if (threadIdx.x < N_CLASSES) { lh0[threadIdx.x] = 0u; lh1[threadIdx.x] = 0u; }
    __syncthreads();

    // per-thread 16-bit packed totals: lo16 = group0, hi16 = group1
    unsigned int cnt[N_CLASSES];
    #pragma unroll
    for (int p = 0; p < N_CLASSES; ++p) cnt[p] = 0u;

    const vint4* __restrict__ p4 = (const vint4*)preds;
    const vint4* __restrict__ a4 = (const vint4*)attrs;

    const int span = BDIM * ITEMS;                      // int4s covered by one block-superiteration
    for (int S = blockIdx.x * span; S < n4; S += gridDim.x * span) {
        const int s = S + (int)threadIdx.x;
        // accT: per-class TOTAL count (7-bit fields); acc1: per-class group-1 count.
        unsigned long long accT = 0ull, acc1 = 0ull;

        if (S + span <= n4) {
            // fast path: 16 named quads, all loads issued, then a register pin
            // that forces every destination to be live at once.
            vint4 P0, P1, P2, P3, P4, P5, P6, P7;
            vint4 A0, A1, A2, A3, A4, A5, A6, A7;
            #define LD(i) P##i = p4[s + i * BDIM]; A##i = a4[s + i * BDIM];
            LD(0) LD(1) LD(2) LD(3) LD(4) LD(5) LD(6) LD(7)
            #undef LD
            asm volatile("" :
                "+v"(P0), "+v"(P1), "+v"(P2), "+v"(P3),
                "+v"(P4), "+v"(P5), "+v"(P6), "+v"(P7),
                "+v"(A0), "+v"(A1), "+v"(A2), "+v"(A3),
                "+v"(A4), "+v"(A5), "+v"(A6), "+v"(A7));

            #define CONSUME(i) { \
                { unsigned long long inc = 1ull << (7 * P##i.x); accT += inc; acc1 += (A##i.x == 0) ? 0ull : inc; } \
                { unsigned long long inc = 1ull << (7 * P##i.y); accT += inc; acc1 += (A##i.y == 0) ? 0ull : inc; } \
                { unsigned long long inc = 1ull << (7 * P##i.z); accT += inc; acc1 += (A##i.z == 0) ? 0ull : inc; } \
                { unsigned long long inc = 1ull << (7 * P##i.w); accT += inc; acc1 += (A##i.w == 0) ? 0ull : inc; } \
            }
            CONSUME(0) CONSUME(1) CONSUME(2) CONSUME(3)
            CONSUME(4) CONSUME(5) CONSUME(6) CONSUME(7)
            #undef CONSUME
        } else {
            // masked tail superiteration
            for (int k = 0; k < ITEMS; ++k) {
                const int idx = s + k * BDIM;
                if (idx < n4) {
                    vint4 pp = p4[idx];
                    vint4 aa = a4[idx];
                    {
                        unsigned long long inc = 1ull << (7 * pp.x);
                        accT += inc; acc1 += (aa.x == 0) ? 0ull : inc;
                    }
                    {
                        unsigned long long inc = 1ull << (7 * pp.y);
                        accT += inc; acc1 += (aa.y == 0) ? 0ull : inc;
                    }
                    {
                        unsigned long long inc = 1ull << (7 * pp.z);
                        accT += inc; acc1 += (aa.z == 0) ? 0ull : inc;
                    }
                    {
                        unsigned long long inc = 1ull << (7 * pp.w);
                        accT += inc; acc1 += (aa.w == 0) ? 0ull : inc;
                    }
                }
            }
        }

        // flush 7-bit windows (<=32 per field) into 16-bit packed totals.
        // group0 = total - group1.
        #pragma unroll
        for (int p = 0; p < N_CLASSES; ++p) {
            unsigned int ct = (unsigned int)(accT >> (7 * p)) & 127u;
            unsigned int c1 = (unsigned int)(acc1 >> (7 * p)) & 127u;
            cnt[p] += (ct - c1) | (c1 << 16);
        }
    }

    // scalar remainder (n % 4), block 0 only: <=3 items
    if (blockIdx.x == 0) {
        for (int t = n4 * 4 + (int)threadIdx.x; t < n; t += BDIM)
            cnt[preds[t]] += (attrs[t] == 0) ? 1u : 0x10000u;
    }

    // wave-64 butterfly; 16-bit halves hold <=64*32 = 2048 here — no carry
    #pragma unroll
    for (int m = 1; m < 64; m <<= 1) {
        #pragma unroll
        for (int p = 0; p < N_CLASSES; ++p)
            cnt[p] += __shfl_xor(cnt[p], m, 64);
    }

    // wave leaders -> block LDS (u32 per group)
    if ((threadIdx.x & 63) == 0) {
        #pragma unroll
        for (int p = 0; p < N_CLASSES; ++p) {
            atomicAdd(&lh0[p], cnt[p] & 0xFFFFu);
            atomicAdd(&lh1[p], cnt[p] >> 16);
        }
    }
    __syncthreads();

    // plain stores — no global atomics
    if (threadIdx.x < NBINS) {
        int c = threadIdx.x >> 1;
        unsigned int v = (threadIdx.x & 1) ? lh1[c] : lh0[c];
        partials[blockIdx.x * NBINS + threadIdx.x] = v;
    }
}

__global__ __launch_bounds__(1024) void spd_finalize_kernel(
    const unsigned int* __restrict__ partials,
    float* __restrict__ out, int nblocks, double n_total)
{
    __shared__ double counts[NBINS];
    const int tid = threadIdx.x;

    if (tid < NBINS * 32) {
        const int bin = tid >> 5;
        const int j = tid & 31;
        unsigned int s = 0u;
        #pragma unroll 8
        for (int b = j; b < nblocks; b += 32)
            s += partials[b * NBINS + bin];
        #pragma unroll
        for (int m = 1; m < 32; m <<= 1)
            s += __shfl_xor(s, m, 32);
        if (j == 0) counts[bin] = (double)s;
    }
    __syncthreads();

    if (tid == 0) {
        double n1 = 0.0;
        #pragma unroll
        for (int c = 0; c < N_CLASSES; ++c)
            n1 += counts[c * N_GROUPS + 1];
        double n0 = n_total - n1;
        double acc = 0.0;
        #pragma unroll
        for (int c = 0; c < N_CLASSES; ++c) {
            double d = counts[c * N_GROUPS] / n0 - counts[c * N_GROUPS + 1] / n1;
            acc += d * d;
        }
        out[0] = (float)acc;
    }
}

extern "C" void kernel_launch(void* const* d_in, const int* in_sizes, int n_in,
                              void* d_out, int out_size, void* d_ws, size_t ws_size,
                              hipStream_t stream)
{
    const int* preds = (const int*)d_in[0];
    const int* attrs = (const int*)d_in[1];
    const int n = in_sizes[0];

    unsigned int* partials = (unsigned int*)d_ws;

    const int n4 = n / 4;
    const int block = BDIM;
    const int per_block = block * ITEMS;              // int4s per block-superiteration
    int grid = (n4 + per_block - 1) / per_block;      // 1024 for N=16.7M
    if (grid > 2048) grid = 2048;
    int max_grid = (int)(ws_size / (NBINS * sizeof(unsigned int)));
    if (grid > max_grid) grid = max_grid;
    if (grid < 1) grid = 1;

    spd_hist_kernel<<<grid, block, 0, stream>>>(preds, attrs, partials, n4, n);
    spd_finalize_kernel<<<1, 1024, 0, stream>>>(partials, (float*)d_out, grid, (double)n);
}